// Round 11
// baseline (459.117 us; speedup 1.0000x reference)
//
#include <hip/hip_runtime.h>
#include <hip/hip_cooperative_groups.h>
#include <cstdint>
#include <cstddef>

namespace cg = cooperative_groups;

// ---------- types ----------
typedef __bf16 bf16x8 __attribute__((ext_vector_type(8)));
typedef __bf16 bf16x4 __attribute__((ext_vector_type(4)));
typedef float  f32x4  __attribute__((ext_vector_type(4)));

// async global->LDS, 16B per lane, dest = wave-uniform base + lane*16
__device__ __forceinline__ void gload_lds16(const void* g, void* l) {
    __builtin_amdgcn_global_load_lds(
        (const __attribute__((address_space(1))) void*)g,
        (__attribute__((address_space(3))) void*)l, 16, 0, 0);
}

// counted-vmcnt "wait + barrier" fences. lgkmcnt(0) retires this wave's
// ds_reads so ring-buffer WAR reuse is protected by the barrier that follows.
#define VM6B asm volatile("s_waitcnt vmcnt(6) lgkmcnt(0)\ns_barrier" ::: "memory")
#define VM4B asm volatile("s_waitcnt vmcnt(4) lgkmcnt(0)\ns_barrier" ::: "memory")
#define VM0B asm volatile("s_waitcnt vmcnt(0) lgkmcnt(0)\ns_barrier" ::: "memory")
#define BARO asm volatile("s_barrier" ::: "memory")
#define WAITB4 asm volatile("s_waitcnt vmcnt(4) lgkmcnt(0)\ns_barrier" ::: "memory")
#define WAITB0 asm volatile("s_waitcnt vmcnt(0) lgkmcnt(0)\ns_barrier" ::: "memory")

// ---------- problem constants ----------
// B=2, S=2048, Hdim=2048, NH=16, KV=4, D=128
#define SEQ 2048
#define NH 16
#define NKV 4
#define HD 128

// ============ 256x256 / BK=64 / 4-phase-per-tile / counted-vmcnt GEMM ============
__device__ __forceinline__ void stage_half(const __bf16* __restrict__ M,
                                           char* dbuf, int bmn, int k0, int half,
                                           int wave, int lane) {
    char* hb = dbuf + (half & 1) * 32768 + (half >> 1) * 16384;
    int kbase = k0 + (half >> 1) * 32;
#pragma unroll
    for (int g = 0; g < 2; ++g) {
        int c = wave * 2 + g;                 // chunk 0..15
        int row = (c & 3) * 64 + lane;        // row in 256-tile
        int ks = c >> 2;                      // slab within half
        gload_lds16(M + (size_t)(bmn + row) * 2048 + kbase + ks * 8, hb + c * 1024);
    }
}

template <int KS, int MH>
__device__ __forceinline__ void phase_mfma(const __bf16* bA, const __bf16* bB,
                                           int quad, int l16, int wr128, int colbase,
                                           bf16x8 (&bq)[4], f32x4 acc[8][4]) {
    bf16x8 af[4];
#pragma unroll
    for (int ii = 0; ii < 4; ++ii)
        af[ii] = *(const bf16x8*)(bA + (KS * 4 + quad) * 2048 +
                                  (wr128 + (MH * 4 + ii) * 16 + l16) * 8);
    if (MH == 0) {
#pragma unroll
        for (int j = 0; j < 4; ++j)
            bq[j] = *(const bf16x8*)(bB + (KS * 4 + quad) * 2048 +
                                     (colbase + (j & 1) * 16 + (j >> 1) * 64 + l16) * 8);
    }
    __builtin_amdgcn_s_setprio(1);
#pragma unroll
    for (int ii = 0; ii < 4; ++ii)
#pragma unroll
        for (int j = 0; j < 4; ++j)
            acc[MH * 4 + ii][j] = __builtin_amdgcn_mfma_f32_16x16x32_bf16(
                af[ii], bq[j], acc[MH * 4 + ii][j], 0, 0, 0);
    __builtin_amdgcn_s_setprio(0);
}

__device__ __forceinline__ void gemm_core(const __bf16* __restrict__ A,
                                          const __bf16* __restrict__ B,
                                          char* lds, int bm, int bn,
                                          int wave, int lane, int quad, int l16,
                                          int wr128, int colbase, f32x4 acc[8][4]) {
    const int NT = 32;  // K = 2048
    stage_half(A, lds, bm, 0, 0, wave, lane);
    stage_half(B, lds, bn, 0, 1, wave, lane);
    stage_half(A, lds, bm, 0, 2, wave, lane);
    stage_half(B, lds, bn, 0, 3, wave, lane);
    int cur = 0;
    for (int t = 0; t < NT - 1; ++t) {
        const __bf16* bA = (const __bf16*)(lds + cur * 65536);
        const __bf16* bB = (const __bf16*)(lds + cur * 65536 + 32768);
        char* nb = lds + (cur ^ 1) * 65536;
        int k1 = (t + 1) * 64;
        bf16x8 bq[4];
        stage_half(A, nb, bm, k1, 0, wave, lane);   // phase 0
        VM6B;
        phase_mfma<0, 0>(bA, bB, quad, l16, wr128, colbase, bq, acc);
        stage_half(B, nb, bn, k1, 1, wave, lane);   // phase 1
        BARO;
        phase_mfma<0, 1>(bA, bB, quad, l16, wr128, colbase, bq, acc);
        stage_half(A, nb, bm, k1, 2, wave, lane);   // phase 2
        VM6B;
        phase_mfma<1, 0>(bA, bB, quad, l16, wr128, colbase, bq, acc);
        stage_half(B, nb, bn, k1, 3, wave, lane);   // phase 3
        BARO;
        phase_mfma<1, 1>(bA, bB, quad, l16, wr128, colbase, bq, acc);
        cur ^= 1;
    }
    {
        const __bf16* bA = (const __bf16*)(lds + cur * 65536);
        const __bf16* bB = (const __bf16*)(lds + cur * 65536 + 32768);
        bf16x8 bq[4];
        VM4B;
        phase_mfma<0, 0>(bA, bB, quad, l16, wr128, colbase, bq, acc);
        phase_mfma<0, 1>(bA, bB, quad, l16, wr128, colbase, bq, acc);
        VM0B;
        phase_mfma<1, 0>(bA, bB, quad, l16, wr128, colbase, bq, acc);
        phase_mfma<1, 1>(bA, bB, quad, l16, wr128, colbase, bq, acc);
    }
}

// ---------- phase 2 worker: fused QKV projection (verbatim r10 body) ----------
__device__ __forceinline__ void qkv_phase(char* lds, int wg0,
                                          const __bf16* __restrict__ hB,
                                          const __bf16* __restrict__ Wqk,
                                          const __bf16* __restrict__ Wv,
                                          __bf16* __restrict__ Qr,
                                          __bf16* __restrict__ Kr,
                                          __bf16* __restrict__ VT) {
    const int tid = threadIdx.x;
    const int wave = tid >> 6, lane = tid & 63;
    const int quad = lane >> 4, l16 = lane & 15;
    const int wr = wave >> 2, wc = wave & 3;
    int wg = (wg0 & 7) * 24 + (wg0 >> 3);   // XCD bijective swizzle on [0,192)
    const int x = wg & 15, y = wg >> 4;
    const bool isVT = (y >= 10);
    const bool isQ = (y < 8);

    const __bf16* Amat = isVT ? Wv : hB;
    const __bf16* Bmat = isVT ? hB : (isQ ? Wqk : Wqk + 2048 * 2048);
    const int bm = isVT ? (y - 10) * 256 : x * 256;
    const int bn = isVT ? x * 256 : (isQ ? y * 256 : (y - 8) * 256);

    const int wr128 = wr * 128;
    const int colbase = (wc >> 1) * 128 + (wc & 1) * 32;

    f32x4 acc[8][4] = {};
    gemm_core(Amat, Bmat, lds, bm, bn, wave, lane, quad, l16, wr128, colbase, acc);

    if (isVT) {
#pragma unroll
        for (int i = 0; i < 8; ++i)
#pragma unroll
            for (int j = 0; j < 4; ++j) {
                int row = bm + wr128 + i * 16 + quad * 4;
                int col = bn + colbase + (j & 1) * 16 + (j >> 1) * 64 + l16;
#pragma unroll
                for (int r = 0; r < 4; ++r)
                    VT[(size_t)(row + r) * 4096 + col] = (__bf16)acc[i][j][r];
            }
    } else {
        __bf16* outp = isQ ? Qr : Kr;
        // Q scale = log2(e)/sqrt(128): folds softmax exp->exp2 into the
        // projection so attn can use raw v_exp_f32 (2^x). K scale = 1.
        const float sc = isQ ? 0.1275255128608411f : 1.0f;
        const int nh = isQ ? NH : NKV;
        const int hh = (isQ ? y * 2 : (y - 8) * 2) + (wc >> 1);
#pragma unroll
        for (int j2 = 0; j2 < 2; ++j2) {
            int d = (wc & 1) * 32 + j2 * 16 + l16;              // 0..63
            float inv = exp2f(-(float)d * 0.2076205059304601f); // log2(1e4)/64
#pragma unroll
            for (int i = 0; i < 8; ++i)
#pragma unroll
                for (int r = 0; r < 4; ++r) {
                    int m = bm + wr128 + i * 16 + quad * 4 + r;
                    int s = m & (SEQ - 1), b = m >> 11;
                    float f = (float)s * inv;
                    float c = __cosf(f) * sc, sn = __sinf(f) * sc;
                    float x1 = acc[i][j2][r], x2 = acc[i][j2 + 2][r];
                    size_t rb = ((size_t)(b * nh + hh) * SEQ + s) * HD;
                    outp[rb + d]      = (__bf16)(x1 * c - x2 * sn);
                    outp[rb + d + 64] = (__bf16)(x2 * c + x1 * sn);
                }
        }
    }
}

// ---------- phase 3 worker: flash attention half-block (verbatim r10 body) ----------
// One 4-wave group (wave = (tid>>6)&3) with its own ring + Pb region.
__device__ __forceinline__ void attn_phase(char* ring, __bf16 (*Pb)[32][40], int v,
                                           const __bf16* __restrict__ Q,
                                           const __bf16* __restrict__ Kr,
                                           const __bf16* __restrict__ VT,
                                           __bf16* __restrict__ AO) {
    const int tid = threadIdx.x;
    const int wave = (tid >> 6) & 3, lane = tid & 63;
    const int quad = lane >> 4, l16 = lane & 15;
    int wg = (v & 7) * 64 + (v >> 3);        // XCD swizzle on [0,512)
    const int x = wg & 15, h = (wg >> 4) & 15, b = wg >> 8;
    const int kv = h >> 2;
    const int qbase = x * 128 + wave * 32;

    // Q fragments in registers (scaled by log2e/sqrt(D) at projection time)
    bf16x8 qf[2][4];
#pragma unroll
    for (int qs = 0; qs < 2; ++qs) {
        const __bf16* Qp =
            Q + ((size_t)(b * NH + h) * SEQ + qbase + qs * 16 + l16) * HD + quad * 8;
#pragma unroll
        for (int kq = 0; kq < 4; ++kq) qf[qs][kq] = *(const bf16x8*)(Qp + kq * 32);
    }

    const __bf16* Kp = Kr + (size_t)(b * NKV + kv) * SEQ * HD;
    const __bf16* Vp = VT + (size_t)(kv * HD) * (2 * SEQ) + b * SEQ;

    f32x4 oacc[2][8] = {};
    float lpart[2] = {0.f, 0.f};

    auto stage = [&](int sb, int k0) {
        char* dst = ring + sb * 16384;
#pragma unroll
        for (int tt = 0; tt < 4; ++tt) {
            int c = wave * 4 + tt;              // chunk 0..15
            if (c < 8) {                        // kt: slabs 2c,2c+1
                gload_lds16(Kp + (size_t)(k0 + (lane & 31)) * HD +
                                (2 * c + (lane >> 5)) * 8,
                            dst + c * 1024);
            } else {                            // vt: kslab vc>>1, d-half vc&1
                int vc = c - 8;
                gload_lds16(Vp + (size_t)(((vc & 1) << 6) + lane) * (2 * SEQ) + k0 +
                                (vc >> 1) * 8,
                            dst + 8192 + vc * 1024);
            }
        }
    };

    auto compute = [&](int cb) {
        const __bf16* kt = (const __bf16*)(ring + cb * 16384);  // [16][32][8]
        const __bf16* vt = kt + 4096;                            // [4][128][8]
        // S^T tile (32 q x 32 kpos per q-set): ka shared by both q-sets
#pragma unroll
        for (int mt = 0; mt < 2; ++mt) {
            f32x4 s0 = {0.f, 0.f, 0.f, 0.f}, s1 = {0.f, 0.f, 0.f, 0.f};
#pragma unroll
            for (int kq = 0; kq < 4; ++kq) {
                bf16x8 ka = *(const bf16x8*)(kt + (kq * 4 + quad) * 256 +
                                             (mt * 16 + l16) * 8);
                s0 = __builtin_amdgcn_mfma_f32_16x16x32_bf16(ka, qf[0][kq], s0, 0, 0, 0);
                s1 = __builtin_amdgcn_mfma_f32_16x16x32_bf16(ka, qf[1][kq], s1, 0, 0, 0);
            }
            bf16x4 pk0, pk1;
#pragma unroll
            for (int r = 0; r < 4; ++r) {
                // Q pre-scaled by log2e/sqrt(D): raw v_exp_f32 (2^x), single inst
                float p0 = __builtin_amdgcn_exp2f(s0[r]);
                float p1 = __builtin_amdgcn_exp2f(s1[r]);
                lpart[0] += p0; lpart[1] += p1;
                pk0[r] = (__bf16)p0; pk1[r] = (__bf16)p1;
            }
            *(bf16x4*)&Pb[wave][l16][mt * 16 + quad * 4] = pk0;
            *(bf16x4*)&Pb[wave][16 + l16][mt * 16 + quad * 4] = pk1;
        }
        // O^T += VT_tile @ P^T; va shared by both q-sets
        bf16x8 pb0 = *(const bf16x8*)&Pb[wave][l16][quad * 8];
        bf16x8 pb1 = *(const bf16x8*)&Pb[wave][16 + l16][quad * 8];
#pragma unroll
        for (int mt = 0; mt < 8; ++mt) {
            bf16x8 va = *(const bf16x8*)(vt + quad * 1024 + (mt * 16 + l16) * 8);
            oacc[0][mt] = __builtin_amdgcn_mfma_f32_16x16x32_bf16(
                va, pb0, oacc[0][mt], 0, 0, 0);
            oacc[1][mt] = __builtin_amdgcn_mfma_f32_16x16x32_bf16(
                va, pb1, oacc[1][mt], 0, 0, 0);
        }
    };

    // 64 tiles of kpos-32; 3-ring: stage targets cb+2 (WAR-safe), WAITB4 counted.
    // Both half-blocks run identical trip counts -> 512-thread barriers align.
    stage(0, 0);
    stage(1, 32);
    int cb = 0;
    for (int t = 0; t < 63; ++t) {
        WAITB4;                                   // tile t landed; t+1 in flight
        if (t < 62) {
            int sb = cb + 2; if (sb >= 3) sb -= 3;
            stage(sb, (t + 2) * 32);
        }
        compute(cb);
        if (++cb == 3) cb = 0;
    }
    WAITB0;                                       // final tile: drain
    compute(cb);

    // epilogue: normalize in-kernel, write bf16 AO
#pragma unroll
    for (int qs = 0; qs < 2; ++qs) {
        lpart[qs] += __shfl_xor(lpart[qs], 16);
        lpart[qs] += __shfl_xor(lpart[qs], 32);
        float inv = 1.f / lpart[qs];
        int q = qbase + qs * 16 + l16;
#pragma unroll
        for (int mt = 0; mt < 8; ++mt) {
            bf16x4 ov;
#pragma unroll
            for (int r = 0; r < 4; ++r) ov[r] = (__bf16)(oacc[qs][mt][r] * inv);
            *(bf16x4*)(AO + ((size_t)(b * SEQ + q)) * (NH * HD) + h * HD +
                       mt * 16 + quad * 4) = ov;
        }
    }
}

// ---------- phase 4 worker: B^T GEMM Wo projection (verbatim r10 body) ----------
__device__ __forceinline__ void bt_phase(char* lds, int wg0,
                                         const __bf16* __restrict__ A,
                                         const __bf16* __restrict__ W,
                                         float* __restrict__ C) {
    const int tid = threadIdx.x;
    const int wave = tid >> 6, lane = tid & 63;
    const int quad = lane >> 4, l16 = lane & 15;
    const int wr = wave >> 2, wc = wave & 3;        // wave tile 64x64
    int wg = (wg0 & 7) * 32 + (wg0 >> 3);           // XCD swizzle on [0,256)
    const int bm = (wg & 31) * 128, bn = (wg >> 5) * 256;

    f32x4 acc[4][4] = {};

    auto stageT = [&](int sb, int k0) {
        char* dst = lds + sb * 49152;
#pragma unroll
        for (int tt = 0; tt < 6; ++tt) {
            int c = wave * 6 + tt;              // 0..47
            if (c < 16) {
                int row = ((c & 1) << 6) + lane;
                gload_lds16(A + (size_t)(bm + row) * 2048 + k0 + (c >> 1) * 8,
                            dst + c * 1024);
            } else {
                int vc = c - 16;
                int row = ((vc & 3) << 6) + lane;
                gload_lds16(W + (size_t)(bn + row) * 2048 + k0 + (vc >> 2) * 8,
                            dst + 16384 + vc * 1024);
            }
        }
    };

    auto computeT = [&](int cb2) {
        const __bf16* bA = (const __bf16*)(lds + cb2 * 49152);  // [8][128][8]
        const __bf16* bB = bA + 8192;                            // [8][256][8]
#pragma unroll
        for (int ks = 0; ks < 2; ++ks) {
            bf16x8 af[4], bq[4];
#pragma unroll
            for (int i = 0; i < 4; ++i)
                af[i] = *(const bf16x8*)(bA + (ks * 4 + quad) * 1024 +
                                         (wr * 64 + i * 16 + l16) * 8);
#pragma unroll
            for (int j = 0; j < 4; ++j)
                bq[j] = *(const bf16x8*)(bB + (ks * 4 + quad) * 2048 +
                                         (wc * 64 + j * 16 + l16) * 8);
            __builtin_amdgcn_s_setprio(1);
#pragma unroll
            for (int i = 0; i < 4; ++i)
#pragma unroll
                for (int j = 0; j < 4; ++j)
                    acc[i][j] = __builtin_amdgcn_mfma_f32_16x16x32_bf16(
                        af[i], bq[j], acc[i][j], 0, 0, 0);
            __builtin_amdgcn_s_setprio(0);
        }
    };

    stageT(0, 0);
    stageT(1, 64);
    int cb = 0;
    for (int t = 0; t < 31; ++t) {
        VM6B;
        if (t < 30) {
            int sb = cb + 2; if (sb >= 3) sb -= 3;
            stageT(sb, (t + 2) * 64);
        }
        computeT(cb);
        if (++cb == 3) cb = 0;
    }
    VM0B;
    computeT(cb);

#pragma unroll
    for (int i = 0; i < 4; ++i)
#pragma unroll
        for (int j = 0; j < 4; ++j) {
            int row = bm + wr * 64 + i * 16 + quad * 4;
            int col = bn + wc * 64 + j * 16 + l16;
#pragma unroll
            for (int r = 0; r < 4; ++r)
                C[(size_t)(row + r) * 2048 + col] = acc[i][j][r];
        }
}

// ---------- cooperative mega-kernel: cvt -> qkv(+Wo cvt) -> attn -> bt ----------
// 256 blocks x 512 threads, 1 block/CU (144 KB LDS). Grid syncs replace
// kernel boundaries (saves 3 launch gaps); Wo conversion runs on qkv's 64
// idle blocks (free). attn = two independent 4-wave groups per block with
// aligned barrier schedules (preserves the proven 2-streams/CU residency).
__global__ __launch_bounds__(512, 1) void mega(const float* __restrict__ hs,
                                               const float* __restrict__ wq,
                                               const float* __restrict__ wk,
                                               const float* __restrict__ wv,
                                               const float* __restrict__ wo,
                                               __bf16* __restrict__ hB,
                                               __bf16* __restrict__ WqkB,
                                               __bf16* __restrict__ WvB,
                                               __bf16* __restrict__ WoB,
                                               __bf16* __restrict__ Qr,
                                               __bf16* __restrict__ Kr,
                                               __bf16* __restrict__ VT,
                                               __bf16* __restrict__ AO,
                                               float* __restrict__ out) {
    __shared__ __align__(16) char smem[147456];   // 144 KB (union of phases)
    cg::grid_group grid = cg::this_grid();
    const int tid = threadIdx.x;
    const int rb = blockIdx.x;                    // 0..255

    // ---- phase 1: cvt hB / WqkB / WvB (14336 virtual 256-lane blocks) ----
    {
        int half = tid >> 8, t256 = tid & 255;
        for (int it = 0; it < 28; ++it) {
            int vb = it * 512 + rb * 2 + half;    // [0, 14336)
            const float* in; __bf16* outp; int base;
            if (vb < 8192)       { in = hs; outp = hB;               base = vb; }
            else if (vb < 12288) { in = wq; outp = WqkB;             base = vb - 8192; }
            else if (vb < 13312) { in = wk; outp = WqkB + 2048*2048; base = vb - 12288; }
            else                 { in = wv; outp = WvB;              base = vb - 13312; }
            int i = base * 256 + t256;
            float4 v = ((const float4*)in)[i];
            bf16x4 o = { (__bf16)v.x, (__bf16)v.y, (__bf16)v.z, (__bf16)v.w };
            ((bf16x4*)outp)[i] = o;
        }
    }
    grid.sync();

    // ---- phase 2: qkv on blocks 0..191; blocks 192..255 convert WoB ----
    if (rb < 192) {
        qkv_phase(smem, rb, hB, WqkB, WvB, Qr, Kr, VT);
    } else {
        // Wo: 4M floats = 1,048,576 float4 over 64 blocks x 512 thr x 32 iters
        int bbase = rb - 192;
        for (int it = 0; it < 32; ++it) {
            int idx = (it * 64 + bbase) * 512 + tid;
            float4 v = ((const float4*)wo)[idx];
            bf16x4 o = { (__bf16)v.x, (__bf16)v.y, (__bf16)v.z, (__bf16)v.w };
            ((bf16x4*)WoB)[idx] = o;
        }
    }
    grid.sync();

    // ---- phase 3: attention, two independent 4-wave groups per block ----
    {
        int g = tid >> 8;                         // half-block 0/1
        char* ring = smem + g * 49152;            // 48 KB each
        __bf16 (*Pb)[32][40] = (__bf16(*)[32][40])(smem + 98304 + g * 10240);
        attn_phase(ring, Pb, rb * 2 + g, Qr, Kr, VT, AO);
    }
    grid.sync();

    // ---- phase 4: output projection ----
    bt_phase(smem, rb, AO, WoB, out);
}

// ---------- launch ----------
extern "C" void kernel_launch(void* const* d_in, const int* in_sizes, int n_in,
                              void* d_out, int out_size, void* d_ws, size_t ws_size,
                              hipStream_t stream) {
    const float* hs = (const float*)d_in[0];
    const float* Wq = (const float*)d_in[1];
    const float* Wk = (const float*)d_in[2];
    const float* Wv = (const float*)d_in[3];
    const float* Wo = (const float*)d_in[4];
    float* out = (float*)d_out;
    char* ws = (char*)d_ws;

    // workspace layout (bytes):
    //   Qr   [0,      16.78M)  [B][NH][S][D]
    //   Kr   [16.78M, 20.97M)  [B][KV][S][D]
    //   VT   [20.97M, 25.17M)  [KV*D][B*S]
    //   WoB  [25.17M, 33.56M)  [2048][2048]
    //   hB   [33.56M, 50.33M)  (dead after qkv)  -> AO alias (16.8 MB)
    //   WqkB [50.33M, 60.82M)  (dead after qkv)
    //   WvB  [60.82M, 62.91M)  (dead after qkv)
    __bf16* Qr   = (__bf16*)(ws + 0);
    __bf16* Kr   = (__bf16*)(ws + 16777216);
    __bf16* VT   = (__bf16*)(ws + 20971520);
    __bf16* WoB  = (__bf16*)(ws + 25165824);
    __bf16* hB   = (__bf16*)(ws + 33554432);
    __bf16* WqkB = (__bf16*)(ws + 50331648);
    __bf16* WvB  = (__bf16*)(ws + 60817408);
    __bf16* AO   = (__bf16*)(ws + 33554432);  // alias hB (dead after qkv)

    void* kargs[] = { (void*)&hs, (void*)&Wq, (void*)&Wk, (void*)&Wv, (void*)&Wo,
                      (void*)&hB, (void*)&WqkB, (void*)&WvB, (void*)&WoB,
                      (void*)&Qr, (void*)&Kr, (void*)&VT, (void*)&AO, (void*)&out };
    hipLaunchCooperativeKernel((const void*)mega, dim3(256), dim3(512),
                               kargs, 0, stream);
}